// Round 1
// baseline (70.346 us; speedup 1.0000x reference)
//
#include <hip/hip_runtime.h>

// x[b,i,p,j,q,l,r] = sum_k y[b,k,i,j,l] * W[k,0,p,q,r]
// y: (4,64,64,8,8) f32 ; W: (64,1,16,4,4) f32 ; out: (4,1,1024,32,32) f32
// Per (b,i) this is a GEMM: [jl=64] x [k=64] -> [pqr=256].
//
// v3 design: wave = 64 lanes = all 64 pq columns (float4 over r).
//   - Each wave owns ONE j (8 jl rows, l=0..7): y[b,k,i,j,:] is wave-uniform
//     -> s_load into SGPRs (readfirstlane-forced), feeds v_fmac as the scalar
//     operand. y costs zero LDS traffic and zero VGPRs.
//   - W staged whole in LDS (64 KB); k-loop reads ws[k*64+lane]: 64
//     consecutive float4 per wave = conflict-free full-BW ds_read_b128.
//   - Inner loop: 1 ds_read_b128 per 32 fmacs (was 2 per 16) -> VALU-bound.
// Grid 512 = (b,i)x(jhalf); block 256 (4 waves, j = jh*4+w). LDS 64 KB ->
// 2 blocks/CU, grid = exactly 2 blocks/CU resident, single round.

__device__ __forceinline__ void fma4(float4& a, float s, const float4& w) {
    a.x += s * w.x; a.y += s * w.y; a.z += s * w.z; a.w += s * w.w;
}

__global__ __launch_bounds__(256, 2) void backproj_kernel(
    const float* __restrict__ y, const float* __restrict__ W,
    float* __restrict__ out)
{
    // W tile: [k][pq] float4 over r = 64 KB. Reused as 32 KB output staging.
    __shared__ float4 ws[64 * 64];

    const int tid = threadIdx.x;
    const int blk = blockIdx.x;
    const int bi  = blk >> 1;            // b*64 + i
    const int jh  = blk & 1;             // j in [jh*4, jh*4+4)
    const int b   = bi >> 6;
    const int i   = bi & 63;

    // ---- stage all of W: 4096 float4, fully coalesced flat copy ----
    const float4* Wg4 = (const float4*)W;    // flat = k*64 + p*4 + q
    #pragma unroll
    for (int t = 0; t < 16; ++t) {
        int f = tid + t * 256;
        ws[f] = Wg4[f];
    }
    __syncthreads();

    const int lane = tid & 63;                                // pq = p*4+q
    const int w    = __builtin_amdgcn_readfirstlane(tid >> 6); // wave 0..3
    const int j    = jh * 4 + w;

    // Wave-uniform y row base: y[b, k, i, j, l=0..7], k-stride 4096 floats.
    const float* ybase = y + (((size_t)b * 64) * 64 + i) * 64 + j * 8;

    float4 acc[8];
    #pragma unroll
    for (int m = 0; m < 8; ++m) acc[m] = float4{0.f, 0.f, 0.f, 0.f};

    #pragma unroll 8
    for (int k = 0; k < 64; ++k) {
        float4 wk = ws[k * 64 + lane];            // conflict-free b128
        const float* yp = ybase + (size_t)k * 4096;
        float4 y0 = *(const float4*)(yp);         // uniform -> s_load_dwordx4
        float4 y1 = *(const float4*)(yp + 4);
        fma4(acc[0], y0.x, wk); fma4(acc[1], y0.y, wk);
        fma4(acc[2], y0.z, wk); fma4(acc[3], y0.w, wk);
        fma4(acc[4], y1.x, wk); fma4(acc[5], y1.y, wk);
        fma4(acc[6], y1.z, wk); fma4(acc[7], y1.w, wk);
    }

    __syncthreads();   // everyone done reading ws -> reuse as staging

    // ---- stage output tile (swizzled), then fully coalesced store ----
    // Out float4 index within bi: p*256 + j*32 + q*8 + l.
    // Block-local: lidx = p*128 + w*32 + q*8 + m  in [0,2048).
    // Naive layout: lidx%8 == m for all 64 lanes -> one bank-group; XOR the
    // low 3 bits with p&7 ( == (lidx>>7)&7 ) to spread across all banks.
    {
        const int p = lane >> 2, q = lane & 3;
        #pragma unroll
        for (int m = 0; m < 8; ++m) {
            int lidx = p * 128 + w * 32 + q * 8 + m;
            ws[lidx ^ ((lidx >> 7) & 7)] = acc[m];
        }
    }
    __syncthreads();

    float4* og4 = (float4*)out + (size_t)bi * 4096 + jh * 128;
    #pragma unroll
    for (int t = 0; t < 8; ++t) {
        int idx = tid + t * 256;                 // [0,2048)
        int pp  = idx >> 7, rem = idx & 127;
        og4[pp * 256 + rem] = ws[idx ^ ((idx >> 7) & 7)];
    }
}

extern "C" void kernel_launch(void* const* d_in, const int* in_sizes, int n_in,
                              void* d_out, int out_size, void* d_ws, size_t ws_size,
                              hipStream_t stream) {
    const float* y = (const float*)d_in[0];   // 4*64*64*8*8 = 1048576 floats
    const float* W = (const float*)d_in[1];   // 64*1*16*4*4 = 16384 floats
    float* out = (float*)d_out;               // 4*1*1024*32*32 = 4194304 floats
    backproj_kernel<<<dim3(512), dim3(256), 0, stream>>>(y, W, out);
}